// Round 9
// baseline (48.635 us; speedup 1.0000x reference)
//
#include <hip/hip_runtime.h>

#define T_DIM 512
#define B_DIM 64
#define V_DIM 1296
#define S_DIM 30
#define LN2   0.6931471805599453f

typedef float v2f __attribute__((ext_vector_type(2)));

// DPP helper. bound_ctrl=true -> lanes with no source read 0.
template<int CTRL, bool BC>
__device__ __forceinline__ float dppf(float src, float old) {
    return __int_as_float(__builtin_amdgcn_update_dpp(
        __float_as_int(old), __float_as_int(src), CTRL, 0xF, 0xF, BC));
}

// ---------------------------------------------------------------------------
// Kernel 1: gather. 2048 blocks x 256 threads, one (b,t,slot) unit each.
// Linear thread index i == compact element index -> coalesced float4 store.
// 3 scattered loads/thread; 32 waves/CU keeps per-CU miss slots full.
// ---------------------------------------------------------------------------
__global__ __launch_bounds__(256)
void ctc_gather_kernel(const float* __restrict__ log_probs,
                       const int*   __restrict__ targets,
                       const int*   __restrict__ input_lengths,
                       float4*      __restrict__ compact,   // (B,T,16)
                       unsigned*    __restrict__ counter)
{
    const int i = blockIdx.x * 256 + threadIdx.x;   // < 64*512*16
    const int b = i >> 13;                          // / (512*16)
    const int t = (i >> 4) & (T_DIM - 1);
    const int s = i & 15;
    if (i == 0) *counter = 0u;                      // zero K2's reduce counter
    if (t >= input_lengths[b]) return;              // skip past-length rows

    int lab0 = 0, lab1 = 0;
    if (s < 15) {
        lab0 = targets[b * S_DIM + 2 * s];
        lab1 = targets[b * S_DIM + 2 * s + 1];
    }
    const float* row = log_probs + ((size_t)t * B_DIM + b) * V_DIM;
    float vc = row[0];
    float va = row[lab0];                           // s==15: row[0] (same line)
    float vb = row[lab1];
    float wb = __expf(vc);
    float w0 = (s < 15) ? __expf(va) : 0.f;         // lane15 labels don't exist
    float w1 = (s < 15) ? __expf(vb) : 0.f;
    compact[i] = make_float4(w0, w1, wb, wb);
}

// ---------------------------------------------------------------------------
// One 32-step chunk of the quad-packed scaled CTC recursion, reading straight
// from global compact with a 32-deep register pipeline (refill chunk c+1).
// Lane l (0..15): X=(alpha[4l],alpha[4l+2]) blanks, Y=(alpha[4l+1],alpha[4l+3])
// labels, scaled by 2^E. MODE 0: chunk 0 (t=0 init). MODE 1: full. MODE 2: pred.
// ---------------------------------------------------------------------------
template<int MODE>
__device__ __forceinline__ void scan_chunk32(const float4* __restrict__ gp,
                                             float4 (&buf)[32], int c, int len,
                                             int lane, v2f S, v2f& X, v2f& Y,
                                             int& E)
{
    float mred = 0.f;
#pragma unroll
    for (int ii = 0; ii < 32; ++ii) {
        float4 w = buf[ii];
        if (c < 15) buf[ii] = gp[(size_t)((c + 1) * 32 + ii) * 16];  // refill +32

        if (MODE == 0 && ii == 0) {
            bool l0 = (lane == 0);
            X = (v2f){ l0 ? ldexpf(w.z, 64) : 0.f, 0.f };   // alpha[0] = w_blank
            Y = (v2f){ l0 ? ldexpf(w.x, 64) : 0.f, 0.f };   // alpha[1] = w_lab0
            E = 64;
        } else {
            float q3m = dppf<0x111, true>(Y.y, 0.f);        // alpha[4l-1] from l-1
            v2f Z  = { q3m, Y.x };
            v2f T1 = X + Z;
            v2f T2 = X + Y;
            v2f T3 = __builtin_elementwise_fma(S, Z, T2);   // + skip terms
            v2f Wb = { w.z, w.w };
            v2f Wl = { w.x, w.y };
            v2f Xn = T1 * Wb;
            v2f Yn = T3 * Wl;
            if (MODE == 2) {
                bool act = (c * 32 + ii) < len;
                X = act ? Xn : X;
                Y = act ? Yn : Y;
            } else { X = Xn; Y = Yn; }
        }

        // renorm window of 8: stale snapshot at 3, reduce 4..6 (off-chain),
        // exact power-of-2 rescale at 7.
        if ((ii & 7) == 3) mred = fmaxf(fmaxf(X.x, X.y), fmaxf(Y.x, Y.y));
        if ((ii & 7) == 4) mred = fmaxf(mred, dppf<0x111, true>(mred, 0.f));
        if ((ii & 7) == 5) mred = fmaxf(mred, dppf<0x112, true>(mred, 0.f));
        if ((ii & 7) == 6) mred = fmaxf(mred, dppf<0x114, true>(mred, 0.f));
        if ((ii & 7) == 7) {
            mred = fmaxf(mred, dppf<0x118, true>(mred, 0.f)); // lane15=max(0..15)
            int e15 = (__builtin_amdgcn_readlane(__float_as_int(mred), 15) >> 23) & 0xFF;
            int sfx = 191 - e15;                              // recenter at 2^64
            X = (v2f){ ldexpf(X.x, sfx), ldexpf(X.y, sfx) };
            Y = (v2f){ ldexpf(Y.x, sfx), ldexpf(Y.y, sfx) };
            E += sfx;
        }
    }
}

// ---------------------------------------------------------------------------
// Kernel 2: scan. 64 blocks x 1 wave, no LDS, no barriers. Reads compact
// (L3-resident after K1) with 32 float4 loads in flight.
// ---------------------------------------------------------------------------
__global__ __launch_bounds__(64)
void ctc_scan_kernel(const float4* __restrict__ compact,
                     const int*    __restrict__ targets,
                     const int*    __restrict__ input_lengths,
                     const int*    __restrict__ target_lengths,
                     float*        __restrict__ losses,
                     unsigned*     __restrict__ counter,
                     float*        __restrict__ out)
{
    const int b    = blockIdx.x;
    const int lane = threadIdx.x;
    const int jl   = lane & 15;
    const int len  = input_lengths[b];
    const int tl   = target_lengths[b];

    float s0 = 0.f, s1 = 0.f;
    if (jl < 15) {
        int k0 = 2 * jl;
        int tc = targets[b * S_DIM + k0];
        int tp = (k0 > 0) ? targets[b * S_DIM + k0 - 1] : -1;  // -1 = blank
        s0 = (tc != tp) ? 1.f : 0.f;
        int tn = targets[b * S_DIM + k0 + 1];
        s1 = (tn != tc) ? 1.f : 0.f;
    }
    v2f S = { s0, s1 };
    v2f X = { 0.f, 0.f }, Y = { 0.f, 0.f };
    int E = 0;

    const float4* gp = compact + (size_t)b * T_DIM * 16 + jl;
    float4 buf[32];
#pragma unroll
    for (int i = 0; i < 32; ++i) buf[i] = gp[(size_t)i * 16];  // chunk 0 preload

    for (int c = 0; c < 16; ++c) {
        if (c * 32 >= len) break;                   // wave-uniform
        if (c == 0)                   scan_chunk32<0>(gp, buf, c, len, lane, S, X, Y, E);
        else if ((c + 1) * 32 <= len) scan_chunk32<1>(gp, buf, c, len, lane, S, X, Y, E);
        else                          scan_chunk32<2>(gp, buf, c, len, lane, S, X, Y, E);
    }

    // alpha[2*tl] (pos 60: lane15 X.x) and alpha[2*tl-1] (pos 59: lane14 Y.y)
    int pB_p = 2 * tl, pL_p = 2 * tl - 1;
    float vB = (pB_p & 2) ? ((pB_p & 1) ? Y.y : X.y) : ((pB_p & 1) ? Y.x : X.x);
    float vL = (pL_p & 2) ? ((pL_p & 1) ? Y.y : X.y) : ((pL_p & 1) ? Y.x : X.x);
    float pB = __shfl(vB, pB_p >> 2);
    float pL = __shfl(vL, pL_p >> 2);
    float loss = -LN2 * (__builtin_amdgcn_logf(pB + pL) - (float)E);
    if (!(loss < 1e29f)) loss = 0.f;                // zero_infinity (inf/NaN)
    loss /= (float)tl;

    unsigned old = 0;
    if (lane == 0) {
        losses[b] = loss;
        __threadfence();                            // release per-block loss
        old = atomicAdd(counter, 1u);               // device scope
    }
    old = __shfl(old, 0);
    if (old == 63u) {                               // last block reduces
        __threadfence();                            // acquire
        float v = ((volatile const float*)losses)[lane];
#pragma unroll
        for (int off = 32; off >= 1; off >>= 1)
            v += __shfl_xor(v, off);
        if (lane == 0) out[0] = v * (1.f / (float)B_DIM);
    }
}

extern "C" void kernel_launch(void* const* d_in, const int* in_sizes, int n_in,
                              void* d_out, int out_size, void* d_ws, size_t ws_size,
                              hipStream_t stream)
{
    const float* log_probs      = (const float*)d_in[0];
    const int*   targets        = (const int*)  d_in[1];
    const int*   input_lengths  = (const int*)  d_in[2];
    const int*   target_lengths = (const int*)  d_in[3];
    float*       out            = (float*)d_out;

    // ws layout: compact 8 MB | losses (256 B) | counter
    float4*   compact = (float4*)d_ws;
    float*    losses  = (float*)((char*)d_ws + (size_t)8 * 1024 * 1024);
    unsigned* counter = (unsigned*)((char*)d_ws + (size_t)8 * 1024 * 1024 + 256);

    hipLaunchKernelGGL(ctc_gather_kernel, dim3(2048), dim3(256), 0, stream,
                       log_probs, targets, input_lengths, compact, counter);
    hipLaunchKernelGGL(ctc_scan_kernel, dim3(B_DIM), dim3(64), 0, stream,
                       compact, targets, input_lengths, target_lengths,
                       losses, counter, out);
}

// Round 10
// 45.747 us; speedup vs baseline: 1.0631x; 1.0631x over previous
//
#include <hip/hip_runtime.h>

#define T_DIM 512
#define B_DIM 64
#define V_DIM 1296
#define S_DIM 30
#define LN2   0.6931471805599453f

typedef float v2f __attribute__((ext_vector_type(2)));

// DPP helper. bound_ctrl=true -> lanes with no source read 0.
template<int CTRL, bool BC>
__device__ __forceinline__ float dppf(float src, float old) {
    return __int_as_float(__builtin_amdgcn_update_dpp(
        __float_as_int(old), __float_as_int(src), CTRL, 0xF, 0xF, BC));
}

// ---------------------------------------------------------------------------
// Quad-packed scaled CTC forward chunk (32 steps), consuming from LDS:
// wl[r][s] = float2{exp(lp[lab 2s]), exp(lp[lab 2s+1])}, wb[r] = exp(lp[blank]).
// Lane l (0..15): X=(alpha[4l],alpha[4l+2]) blanks, Y=(alpha[4l+1],alpha[4l+3])
// labels, scaled by 2^E. MODE 0: t=0 init. MODE 1: full. MODE 2: t<len pred.
// ---------------------------------------------------------------------------
template<int MODE>
__device__ __forceinline__ void consume_chunk(const float2* __restrict__ wl,
                                              const float*  __restrict__ wb,
                                              int c, int len, int lane, v2f S,
                                              v2f& X, v2f& Y, int& E)
{
    const int jl = lane & 15;
    float2 bl[8];
    float  bb[8];
#pragma unroll
    for (int i = 0; i < 8; ++i) { bl[i] = wl[i * 16 + jl]; bb[i] = wb[i]; }

    float mred = 0.f;
#pragma unroll
    for (int i = 0; i < 32; ++i) {
        float2 wv  = bl[i & 7];
        float  wbv = bb[i & 7];
        if (i + 8 < 32) { bl[i & 7] = wl[(i + 8) * 16 + jl]; bb[i & 7] = wb[i + 8]; }

        if (MODE == 0 && i == 0) {
            bool l0 = (lane == 0);
            X = (v2f){ l0 ? ldexpf(wbv, 64) : 0.f, 0.f };   // alpha[0] = blank
            Y = (v2f){ l0 ? ldexpf(wv.x, 64) : 0.f, 0.f };  // alpha[1] = label0
            E = 64;
        } else {
            float q3m = dppf<0x111, true>(Y.y, 0.f);        // alpha[4l-1] from l-1
            v2f Z  = { q3m, Y.x };
            v2f T1 = X + Z;
            v2f T2 = X + Y;
            v2f T3 = __builtin_elementwise_fma(S, Z, T2);   // + skip terms
            v2f Wb = { wbv, wbv };
            v2f Wl = { wv.x, wv.y };
            v2f Xn = T1 * Wb;
            v2f Yn = T3 * Wl;
            if (MODE == 2) {
                bool act = (c * 32 + i) < len;
                X = act ? Xn : X;
                Y = act ? Yn : Y;
            } else { X = Xn; Y = Yn; }
        }

        // renorm window of 8: stale snapshot at 3, reduce 4..6 (off-chain),
        // exact power-of-2 rescale at 7.
        if ((i & 7) == 3) mred = fmaxf(fmaxf(X.x, X.y), fmaxf(Y.x, Y.y));
        if ((i & 7) == 4) mred = fmaxf(mred, dppf<0x111, true>(mred, 0.f));
        if ((i & 7) == 5) mred = fmaxf(mred, dppf<0x112, true>(mred, 0.f));
        if ((i & 7) == 6) mred = fmaxf(mred, dppf<0x114, true>(mred, 0.f));
        if ((i & 7) == 7) {
            mred = fmaxf(mred, dppf<0x118, true>(mred, 0.f)); // lane15=max(0..15)
            int e15 = (__builtin_amdgcn_readlane(__float_as_int(mred), 15) >> 23) & 0xFF;
            int sfx = 191 - e15;                              // recenter at 2^64
            X = (v2f){ ldexpf(X.x, sfx), ldexpf(X.y, sfx) };
            Y = (v2f){ ldexpf(Y.x, sfx), ldexpf(Y.y, sfx) };
            E += sfx;
        }
    }
}

// ---------------------------------------------------------------------------
// Fused decoupled kernel: 64 blocks x 576 threads.
// Waves 0-7: producers. Wave w owns whole chunks w and w+8 (chunk = 32 t-rows).
//   All ~48 scattered loads issued up-front (max lines in flight), then
//   exp -> LDS ring -> flag. Only sync: LDS flags (lgkmcnt, no cache invals).
// Wave 8: scanner. Spins on flag[c] (LDS broadcast read), consumes chunk,
//   publishes consumed counter (slot-reuse guard for chunks 8..15).
// ---------------------------------------------------------------------------
__global__ __launch_bounds__(576)
void ctc_fused_kernel(const float* __restrict__ log_probs,
                      const int*   __restrict__ targets,
                      const int*   __restrict__ input_lengths,
                      const int*   __restrict__ target_lengths,
                      float*       __restrict__ losses,
                      unsigned*    __restrict__ counter,
                      float*       __restrict__ out)
{
    __shared__ float2   ring_wl[8 * 32 * 16];   // 32 KB: [slot][row][slot16]
    __shared__ float    ring_wb[8 * 32];        // 1 KB:  [slot][row] blank
    __shared__ unsigned flags[16];
    __shared__ unsigned consumed;

    const int b    = blockIdx.x;
    const int tid  = threadIdx.x;
    const int len  = input_lengths[b];
    const int w    = tid >> 6;
    const int lane = tid & 63;

    if (tid < 16) flags[tid] = 0u;
    if (tid == 16) consumed = 0u;
    __syncthreads();                             // once, before any heavy loads

    if (w < 8) {
        // ------------------------------ producer ------------------------------
        const int s  = lane & 15;
        const int r0 = lane >> 4;                // 0..3
        int labA = 0, labB = 0;
        if (s < 15) {
            labA = targets[b * S_DIM + 2 * s];
            labB = targets[b * S_DIM + 2 * s + 1];
        }
        const float* lpb = log_probs + (size_t)b * V_DIM;

        float vA[2][8], vB[2][8];                // statically indexed (rule #20)
#pragma unroll
        for (int h = 0; h < 2; ++h) {
            const int c = w + 8 * h;
#pragma unroll
            for (int k = 0; k < 8; ++k) {
                int r = r0 + 4 * k;
                int t = c * 32 + r;
                if (t < len) {
                    const float* row = lpb + (size_t)t * (B_DIM * V_DIM);
                    if (s < 15) { vA[h][k] = row[labA]; vB[h][k] = row[labB]; }
                    else        { vA[h][k] = row[0];    vB[h][k] = -1e30f;   }
                } else { vA[h][k] = -1e30f; vB[h][k] = -1e30f; }   // exp -> 0
            }
        }
#pragma unroll
        for (int h = 0; h < 2; ++h) {
            const int c = w + 8 * h;
            if (h == 1) {                        // slot reuse guard (slot = w)
                unsigned guard = 0;
                while (__hip_atomic_load(&consumed, __ATOMIC_ACQUIRE,
                                         __HIP_MEMORY_SCOPE_WORKGROUP) < (unsigned)(w + 1)) {
                    __builtin_amdgcn_s_sleep(1);
                    if (++guard > (1u << 18)) break;
                }
            }
            const int slot = c & 7;
#pragma unroll
            for (int k = 0; k < 8; ++k) {
                int r = r0 + 4 * k;
                if (s < 15) {
                    ring_wl[slot * 512 + r * 16 + s] =
                        make_float2(__expf(vA[h][k]), __expf(vB[h][k]));
                } else {
                    ring_wb[slot * 32 + r] = __expf(vA[h][k]);
                    ring_wl[slot * 512 + r * 16 + 15] = make_float2(0.f, 0.f);
                }
            }
            asm volatile("s_waitcnt lgkmcnt(0)" ::: "memory");   // writes visible
            if (lane == 0)
                __hip_atomic_store(&flags[c], 1u, __ATOMIC_RELEASE,
                                   __HIP_MEMORY_SCOPE_WORKGROUP);
        }
    } else {
        // ------------------------------ scanner -------------------------------
        const int jl = lane & 15;
        const int tl = target_lengths[b];

        float s0 = 0.f, s1 = 0.f;
        if (jl < 15) {
            int k0 = 2 * jl;
            int tc = targets[b * S_DIM + k0];
            int tp = (k0 > 0) ? targets[b * S_DIM + k0 - 1] : -1;  // -1 = blank
            s0 = (tc != tp) ? 1.f : 0.f;
            int tn = targets[b * S_DIM + k0 + 1];
            s1 = (tn != tc) ? 1.f : 0.f;
        }
        v2f S = { s0, s1 };
        v2f X = { 0.f, 0.f }, Y = { 0.f, 0.f };
        int E = 0;

        for (int c = 0; c < 16; ++c) {
            if (c * 32 >= len) break;            // wave-uniform
            unsigned guard = 0;
            while (__hip_atomic_load(&flags[c], __ATOMIC_ACQUIRE,
                                     __HIP_MEMORY_SCOPE_WORKGROUP) == 0u) {
                __builtin_amdgcn_s_sleep(1);
                if (++guard > (1u << 18)) break;
            }
            const float2* wl = &ring_wl[(c & 7) * 512];
            const float*  wb = &ring_wb[(c & 7) * 32];
            if (c == 0)                   consume_chunk<0>(wl, wb, c, len, lane, S, X, Y, E);
            else if ((c + 1) * 32 <= len) consume_chunk<1>(wl, wb, c, len, lane, S, X, Y, E);
            else                          consume_chunk<2>(wl, wb, c, len, lane, S, X, Y, E);
            __hip_atomic_store(&consumed, (unsigned)(c + 1), __ATOMIC_RELEASE,
                               __HIP_MEMORY_SCOPE_WORKGROUP);
        }

        // alpha[2*tl] (pos 60: lane15 X.x) and alpha[2*tl-1] (pos 59: lane14 Y.y)
        int pB_p = 2 * tl, pL_p = 2 * tl - 1;
        float vBv = (pB_p & 2) ? ((pB_p & 1) ? Y.y : X.y) : ((pB_p & 1) ? Y.x : X.x);
        float vLv = (pL_p & 2) ? ((pL_p & 1) ? Y.y : X.y) : ((pL_p & 1) ? Y.x : X.x);
        float pB = __shfl(vBv, pB_p >> 2);
        float pL = __shfl(vLv, pL_p >> 2);
        float loss = -LN2 * (__builtin_amdgcn_logf(pB + pL) - (float)E);
        if (!(loss < 1e29f)) loss = 0.f;         // zero_infinity (inf/NaN)
        loss /= (float)tl;

        unsigned old = 0;
        if (lane == 0) {
            losses[b] = loss;
            __threadfence();                     // release per-block loss
            old = atomicAdd(counter, 1u);        // device scope
        }
        old = __shfl(old, 0);
        if (old == 63u) {                        // last block reduces, lane-parallel
            __threadfence();                     // acquire
            float v = ((volatile const float*)losses)[lane];
#pragma unroll
            for (int off = 32; off >= 1; off >>= 1)
                v += __shfl_xor(v, off);
            if (lane == 0) out[0] = v * (1.f / (float)B_DIM);
        }
    }
}

extern "C" void kernel_launch(void* const* d_in, const int* in_sizes, int n_in,
                              void* d_out, int out_size, void* d_ws, size_t ws_size,
                              hipStream_t stream)
{
    const float* log_probs      = (const float*)d_in[0];
    const int*   targets        = (const int*)  d_in[1];
    const int*   input_lengths  = (const int*)  d_in[2];
    const int*   target_lengths = (const int*)  d_in[3];
    float*       out            = (float*)d_out;
    float*       losses         = (float*)d_ws;                    // 64 floats
    unsigned*    counter        = (unsigned*)((char*)d_ws + 256);  // own line

    hipMemsetAsync(counter, 0, sizeof(unsigned), stream);          // capturable
    hipLaunchKernelGGL(ctc_fused_kernel, dim3(B_DIM), dim3(576), 0, stream,
                       log_probs, targets, input_lengths, target_lengths,
                       losses, counter, out);
}